// Round 9
// baseline (904.611 us; speedup 1.0000x reference)
//
#include <hip/hip_runtime.h>
#include <stdint.h>

#define HIDDEN 512
#define EMBED  256
#define VTGT   50257
#define TLEN   512
#define GATE3  1536
#define REC_B  16
#define GEMM_B 224
#define NBLK   (REC_B + GEMM_B)
#define NJT    ((VTGT + 127) / 128)   // 393 j-tiles of 128

typedef float f32x4 __attribute__((ext_vector_type(4)));
typedef unsigned int u32;
typedef unsigned int u32x4 __attribute__((ext_vector_type(4)));

__device__ __forceinline__ unsigned short f2bf(float f) {
  union { float f; unsigned u; } v; v.f = f;
  unsigned u = v.u;
  unsigned r = (u + 0x7FFFu + ((u >> 16) & 1u)) >> 16;
  return (unsigned short)r;
}

__device__ __forceinline__ float sigm(float x) {
  return __builtin_amdgcn_rcpf(1.f + __expf(-x));
}
__device__ __forceinline__ float fast_tanh(float x) {
  return 1.f - 2.f * __builtin_amdgcn_rcpf(__expf(2.f * x) + 1.f);
}

// single coherent dword poll (one RTT per sample)
__device__ __forceinline__ u32 cpoll(const u32* p) {
  u32 v;
  asm volatile("global_load_dword %0, %1, off sc0 sc1\n\ts_waitcnt vmcnt(0)"
               : "=v"(v) : "v"(p) : "memory");
  return v;
}
// 4x dwordx4 coherent, single flight (staging)
__device__ __forceinline__ void cload4x4(const u32* p, u32x4& a, u32x4& b,
                                         u32x4& c, u32x4& d) {
  asm volatile(
      "global_load_dwordx4 %0, %4, off sc0 sc1\n\t"
      "global_load_dwordx4 %1, %4, off offset:16 sc0 sc1\n\t"
      "global_load_dwordx4 %2, %4, off offset:32 sc0 sc1\n\t"
      "global_load_dwordx4 %3, %4, off offset:48 sc0 sc1\n\t"
      "s_waitcnt vmcnt(0)"
      : "=v"(a), "=v"(b), "=v"(c), "=v"(d) : "v"(p) : "memory");
}
// 2x dwordx4 coherent at p0 and p1, single flight
__device__ __forceinline__ void cload2(const u32* p0, const u32* p1,
                                       u32x4& a, u32x4& b) {
  asm volatile(
      "global_load_dwordx4 %0, %2, off sc0 sc1\n\t"
      "global_load_dwordx4 %1, %3, off sc0 sc1\n\t"
      "s_waitcnt vmcnt(0)"
      : "=v"(a), "=v"(b) : "v"(p0), "v"(p1) : "memory");
}
__device__ __forceinline__ void cstore(u32* p, u32 v) {
  asm volatile("global_store_dword %0, %1, off sc0 sc1" :: "v"(p), "v"(v) : "memory");
}
__device__ __forceinline__ void cstore4(u32* p, u32x4 v) {
  asm volatile("global_store_dwordx4 %0, %1, off sc0 sc1" :: "v"(p), "v"(v) : "memory");
}

// ---------- encoder: gi = Wih_e @ x_last + bih_e ----------
__global__ void kenc1(const int* source, const float* emb_e, const float* Wih_e,
                      const float* bih_e, float* genc) {
  __shared__ float xs[EMBED];
  int tid = threadIdx.x;
  int tok = source[511];
  if (tid < EMBED) xs[tid] = emb_e[(size_t)tok * EMBED + tid];
  __syncthreads();
  int j = blockIdx.x * 256 + tid;
  const float* w = Wih_e + (size_t)j * EMBED;
  float acc = bih_e[j];
  for (int k = 0; k < EMBED; k += 4) {
    float4 wv = *(const float4*)(w + k);
    acc += wv.x * xs[k] + wv.y * xs[k + 1] + wv.z * xs[k + 2] + wv.w * xs[k + 3];
  }
  genc[j] = acc;
}

// ---------- encoder gates: write tagged h_0 into hs slot 0 ----------
__global__ void kenc2(const float* genc, const float* bhh_e, u32* hs) {
  int e = threadIdx.x; // 512 threads
  float r = sigm(genc[e] + bhh_e[e]);
  float z = sigm(genc[e + 512] + bhh_e[e + 512]);
  float n = tanhf(genc[e + 1024] + r * bhh_e[e + 1024]);
  float h = (1.f - z) * n;
  hs[e] = (__float_as_uint(h) & ~511u) | 256u;  // tag(0) = 256
}

// ---------- GI[t][j] = Wih_d @ relu(emb_d[tok_t]) + bih_d ----------
__global__ __launch_bounds__(256) void kgi(const int* target, const float* emb_d,
                                           const float* Wih_d, const float* bih_d,
                                           float* GI) {
  __shared__ float Xs[32][EMBED];
  int tid = threadIdx.x;
  int j0 = blockIdx.x * 128;
  int t0 = blockIdx.y * 32;
  for (int idx = tid; idx < 32 * EMBED; idx += 256) {
    int tt = idx >> 8, c = idx & 255;
    int t = t0 + tt;
    int tok = (t == 0) ? 0 : target[t - 1];
    float v = emb_d[(size_t)tok * EMBED + c];
    Xs[tt][c] = v > 0.f ? v : 0.f;
  }
  __syncthreads();
  int jl = tid & 127, tg = tid >> 7;
  int j = j0 + jl;
  const float* w = Wih_d + (size_t)j * EMBED;
  float acc[16];
#pragma unroll
  for (int i = 0; i < 16; ++i) acc[i] = 0.f;
  for (int k = 0; k < EMBED; k += 4) {
    float4 wv = *(const float4*)(w + k);
#pragma unroll
    for (int i = 0; i < 16; ++i) {
      int tl = tg * 16 + i;
      acc[i] += wv.x * Xs[tl][k] + wv.y * Xs[tl][k + 1] +
                wv.z * Xs[tl][k + 2] + wv.w * Xs[tl][k + 3];
    }
  }
  float b = bih_d[j];
#pragma unroll
  for (int i = 0; i < 16; ++i) {
    int t = t0 + tg * 16 + i;
    GI[(size_t)t * GATE3 + j] = acc[i] + b;
  }
}

// ---------- recurrence: 16 blocks x 512 thr (R7 structure, gathered publish) ----------
__device__ void rec_path(int bid, const float* Whh, const float* bhh,
                         const float* GI, u32* hs, u32* stepv, char* SM) {
  int tid = threadIdx.x;
  int p = tid & 15, r = tid >> 4;     // k-slice 0..15, row 0..31
  int e = bid * 32 + r;
  int k0 = p * 32;
  float* hbuf = (float*)SM;           // [2][576] padded stride 36 per 32
  // weights as vector-typed arrays, constant indices only -> VGPR-resident
  f32x4 wr4[8], wz4[8], wn4[8];
  {
    const f32x4* Wr = (const f32x4*)(Whh + (size_t)e * HIDDEN + k0);
    const f32x4* Wz = (const f32x4*)(Whh + (size_t)(e + 512) * HIDDEN + k0);
    const f32x4* Wn = (const f32x4*)(Whh + (size_t)(e + 1024) * HIDDEN + k0);
#pragma unroll
    for (int i = 0; i < 8; ++i) { wr4[i] = Wr[i]; wz4[i] = Wz[i]; wn4[i] = Wn[i]; }
  }
  float br = bhh[e], bz = bhh[e + 512], bn = bhh[e + 1024];
  float hold = __uint_as_float(hs[e] & ~511u);   // h^0[e], register-resident
  __builtin_amdgcn_s_setprio(1);
  // wave-0 poll geometry: lane handles dwords d0=tid*4 (.. +3) and d0+256
  int d0 = tid * 4;
  int i0 = ((d0 >> 5) * 36) + (d0 & 31);
  int i1 = (((d0 + 256) >> 5) * 36) + (d0 & 31);
  int w = tid >> 6;                               // wave 0..7 (rows 4w..4w+3)
  u32* pubbase = hs + bid * 32 + w * 4;           // + (t+1)*HIDDEN later
  for (int t = 0; t < TLEN; ++t) {
    int par = t & 1;
    float gie = 0.f, giz = 0.f, gin = 0.f;
    if (p == 0) {
      const float* git = GI + (size_t)t * GATE3;
      gie = git[e]; giz = git[e + 512]; gin = git[e + 1024];
    }
    if (tid < 64) {
      const u32* s0 = hs + (size_t)t * HIDDEN + d0;
      const u32* s1 = s0 + 256;
      u32 want = 256u + ((u32)t & 255u);
      u32x4 a, b;
      for (;;) {
        cload2(s0, s1, a, b);
        u32 bad = 0;
#pragma unroll
        for (int q = 0; q < 4; ++q) bad |= (a[q] ^ want) | (b[q] ^ want);
        if (!__any((bad & 511u) != 0u)) break;
      }
      f32x4 fa, fb;
#pragma unroll
      for (int q = 0; q < 4; ++q) {
        fa[q] = __uint_as_float(a[q] & ~511u);
        fb[q] = __uint_as_float(b[q] & ~511u);
      }
      *(f32x4*)&hbuf[par * 576 + i0] = fa;
      *(f32x4*)&hbuf[par * 576 + i1] = fb;
    }
    __syncthreads();
    if (bid == 0 && tid == 0) cstore(stepv, (u32)t);  // slot t globally visible
    const f32x4* hp4 = (const f32x4*)(hbuf + par * 576 + p * 36);
    float pr = 0.f, pz = 0.f, pn = 0.f;
#pragma unroll
    for (int i = 0; i < 8; ++i) {
      f32x4 hv = hp4[i];
      pr += wr4[i][0]*hv[0] + wr4[i][1]*hv[1] + wr4[i][2]*hv[2] + wr4[i][3]*hv[3];
      pz += wz4[i][0]*hv[0] + wz4[i][1]*hv[1] + wz4[i][2]*hv[2] + wz4[i][3]*hv[3];
      pn += wn4[i][0]*hv[0] + wn4[i][1]*hv[1] + wn4[i][2]*hv[2] + wn4[i][3]*hv[3];
    }
#pragma unroll
    for (int m = 1; m < 16; m <<= 1) {
      pr += __shfl_xor(pr, m);
      pz += __shfl_xor(pz, m);
      pn += __shfl_xor(pn, m);
    }
    u32 pk = 0;
    if (p == 0) {
      float rg = sigm(gie + pr + br);
      float z  = sigm(giz + pz + bz);
      float n  = fast_tanh(gin + rg * (pn + bn));
      float hnew = (1.f - z) * n + z * hold;
      hold = hnew;
      pk = (__float_as_uint(hnew) & ~511u) | (256u + ((u32)(t + 1) & 255u));
    }
    // gather the wave's 4 row-values (lanes 0,16,32,48) -> one dwordx4 store
    u32x4 o;
    o[0] = __shfl(pk, 0);  o[1] = __shfl(pk, 16);
    o[2] = __shfl(pk, 32); o[3] = __shfl(pk, 48);
    if ((tid & 63) == 0) cstore4(pubbase + (size_t)(t + 1) * HIDDEN, o);
    // no tail barrier: next step's poller writes the other hbuf parity
  }
  if (bid == 0 && tid < 64) {  // confirm final slot 512 -> stepv = 512
    const u32* s0 = hs + (size_t)TLEN * HIDDEN + d0;
    const u32* s1 = s0 + 256;
    u32 want = 256u + ((u32)TLEN & 255u);
    u32x4 a, b;
    for (;;) {
      cload2(s0, s1, a, b);
      u32 bad = 0;
#pragma unroll
      for (int q = 0; q < 4; ++q) bad |= (a[q] ^ want) | (b[q] ^ want);
      if (!__any((bad & 511u) != 0u)) break;
    }
    if (tid == 0) cstore(stepv, (u32)TLEN);
  }
}

// ---------- GEMM path: tag-verified A staging, on-the-fly bf16 B, fused row-sum ----------
__device__ void gemm_path(int g, const u32* hs, u32* stepv, const float* Wout,
                          const float* bout, float* rs, float* out, char* SM) {
  unsigned short* As = (unsigned short*)SM;       // [64][520] bf16
  float* rsum = (float*)(SM + 64 * 520 * 2);      // [64]
  int tid = threadIdx.x;
  int w = tid >> 6, lane = tid & 63;
  int jl = lane & 15, kq = lane >> 4;
  int srow = tid >> 3, scg = tid & 7;             // stage: row 0..63, 64-dword group
  if (tid < 64) rsum[tid] = 0.f;
  for (int t0i = 0; t0i < 8; ++t0i) {
    int t0 = t0i * 64;
    if (tid == 0) {  // sleep-throttled progress hint (tags stay authoritative)
      while ((int)cpoll(stepv) < t0 + 64) __builtin_amdgcn_s_sleep(16);
    }
    __syncthreads();
    // stage A tile: rows t0..t0+63 from tagged hs slots t0+1..t0+64
    int slot = t0 + srow + 1;
    u32 want = 256u + ((u32)slot & 255u);
    const u32* sbase = hs + (size_t)slot * HIDDEN + scg * 64;
#pragma unroll
    for (int b = 0; b < 4; ++b) {
      const u32* sp = sbase + b * 16;
      u32x4 c0, c1, c2, c3;
      for (;;) {
        cload4x4(sp, c0, c1, c2, c3);
        u32 bad = 0;
#pragma unroll
        for (int q = 0; q < 4; ++q)
          bad |= (c0[q] ^ want) | (c1[q] ^ want) | (c2[q] ^ want) | (c3[q] ^ want);
        if (!(bad & 511u)) break;
      }
      u32 dw[8];
#pragma unroll
      for (int q = 0; q < 4; ++q) {
        u32x4 cq = (q == 0) ? c0 : (q == 1) ? c1 : (q == 2) ? c2 : c3;
        float f0 = __uint_as_float(cq[0] & ~511u);
        float f1 = __uint_as_float(cq[1] & ~511u);
        float f2 = __uint_as_float(cq[2] & ~511u);
        float f3 = __uint_as_float(cq[3] & ~511u);
        dw[q * 2]     = (u32)f2bf(f0) | ((u32)f2bf(f1) << 16);
        dw[q * 2 + 1] = (u32)f2bf(f2) | ((u32)f2bf(f3) << 16);
      }
      *(u32x4*)&As[srow * 520 + scg * 64 + b * 16]     = *(u32x4*)&dw[0];
      *(u32x4*)&As[srow * 520 + scg * 64 + b * 16 + 8] = *(u32x4*)&dw[4];
    }
    __syncthreads();
    for (int jt = g; jt < NJT; jt += GEMM_B) {
      int j = jt * 128 + w * 16 + jl;
      int jc = j < VTGT ? j : VTGT - 1;
      const float* Bp = Wout + (size_t)jc * HIDDEN + kq * 8;
      f32x4 acc[4];
#pragma unroll
      for (int i = 0; i < 4; ++i) acc[i] = (f32x4)(0.f);
#pragma unroll
      for (int ks = 0; ks < 16; ++ks) {
        float4 b0 = *(const float4*)(Bp + ks * 32);
        float4 b1 = *(const float4*)(Bp + ks * 32 + 4);
        u32x4 bf;
        bf[0] = (u32)f2bf(b0.x) | ((u32)f2bf(b0.y) << 16);
        bf[1] = (u32)f2bf(b0.z) | ((u32)f2bf(b0.w) << 16);
        bf[2] = (u32)f2bf(b1.x) | ((u32)f2bf(b1.y) << 16);
        bf[3] = (u32)f2bf(b1.z) | ((u32)f2bf(b1.w) << 16);
#pragma unroll
        for (int tq = 0; tq < 4; ++tq) {
          u32x4 af = *(const u32x4*)&As[(tq * 16 + jl) * 520 + ks * 32 + kq * 8];
          asm volatile("v_mfma_f32_16x16x32_bf16 %0, %1, %2, %0"
                       : "+v"(acc[tq]) : "v"(af), "v"(bf));
        }
      }
      asm volatile("s_nop 7\n\ts_nop 7\n\ts_nop 7" ::);
      bool jok = j < VTGT;
      float bj = jok ? bout[j] : 0.f;
#pragma unroll
      for (int tq = 0; tq < 4; ++tq) {
#pragma unroll
        for (int rr = 0; rr < 4; ++rr) {
          int t = t0 + tq * 16 + kq * 4 + rr;  // D: row=(lane>>4)*4+reg, col=lane&15
          float lg = acc[tq][rr] + bj;
          if (jok) out[(size_t)t * VTGT + j] = lg;
          float ex = jok ? __expf(lg) : 0.f;
#pragma unroll
          for (int m = 1; m < 16; m <<= 1) ex += __shfl_xor(ex, m);
          if (jl == 0) atomicAdd(&rsum[tq * 16 + kq * 4 + rr], ex);
        }
      }
    }
    __syncthreads();  // all As reads + rsum adds done
    if (tid < 64) {
      atomicAdd(rs + t0 + tid, rsum[tid]);
      rsum[tid] = 0.f;
    }
  }
}

// ---------- fused mega-kernel: 16 rec blocks + 224 persistent GEMM blocks ----------
__global__ __launch_bounds__(512, 2) void kmain(const float* Whh, const float* bhh,
                                                const float* GI, u32* hs, u32* stepv,
                                                const float* Wout, const float* bout,
                                                float* rs, float* out) {
  __shared__ __align__(16) char SM[64 * 520 * 2 + 256];  // As+rsum / hbuf union
  int bid = blockIdx.x;
  if (bid < REC_B) rec_path(bid, Whh, bhh, GI, hs, stepv, SM);
  else gemm_path(bid - REC_B, hs, stepv, Wout, bout, rs, out, SM);
}

// ---------- logp = logits - log(rowsum), single pass ----------
__global__ __launch_bounds__(1024) void klsub(float* out, const float* rs) {
  int t = blockIdx.x;
  float l = logf(rs[t]);
  float* row = out + (size_t)t * VTGT;
  for (int jj = threadIdx.x; jj < VTGT; jj += 1024) row[jj] -= l;
}

extern "C" void kernel_launch(void* const* d_in, const int* in_sizes, int n_in,
                              void* d_out, int out_size, void* d_ws, size_t ws_size,
                              hipStream_t stream) {
  const int*   source = (const int*)d_in[0];
  const int*   target = (const int*)d_in[1];
  const float* emb_e  = (const float*)d_in[2];
  const float* Wih_e  = (const float*)d_in[3];
  // d_in[4] = Whh_e: unused (h0 == 0)
  const float* bih_e  = (const float*)d_in[5];
  const float* bhh_e  = (const float*)d_in[6];
  const float* emb_d  = (const float*)d_in[7];
  const float* Wih_d  = (const float*)d_in[8];
  const float* Whh_d  = (const float*)d_in[9];
  const float* bih_d  = (const float*)d_in[10];
  const float* bhh_d  = (const float*)d_in[11];
  const float* Wout   = (const float*)d_in[12];
  const float* bout   = (const float*)d_in[13];
  float* out = (float*)d_out;
  char* ws = (char*)d_ws;

  // ws layout (bytes), 256-aligned
  float* GI    = (float*)(ws + 0);           // 3,145,728
  u32*   hs    = (u32*)(ws + 3145728);       // 1,050,624 (513 x 512 tagged f32)
  u32*   stepv = (u32*)(ws + 4196352);       //       128
  float* rs    = (float*)(ws + 4196480);     //     2,048 (row sum-exp)
  float* genc  = (float*)(ws + 4198528);     //     6,144
  // total ws use ~4.2 MB

  hipMemsetAsync(hs, 0, 1052800, stream);    // hs tags + stepv + rs
  kenc1<<<6, 256, 0, stream>>>(source, emb_e, Wih_e, bih_e, genc);
  kenc2<<<1, 512, 0, stream>>>(genc, bhh_e, hs);
  kgi<<<dim3(12, 16), 256, 0, stream>>>(target, emb_d, Wih_d, bih_d, GI);
  kmain<<<NBLK, 512, 0, stream>>>(Whh_d, bhh_d, GI, hs, stepv, Wout, bout, rs, out);
  klsub<<<512, 1024, 0, stream>>>(out, rs);
}

// Round 10
// 897.179 us; speedup vs baseline: 1.0083x; 1.0083x over previous
//
#include <hip/hip_runtime.h>
#include <stdint.h>

#define HIDDEN 512
#define EMBED  256
#define VTGT   50257
#define TLEN   512
#define GATE3  1536
#define REC_B  16
#define GEMM_B 224
#define NBLK   (REC_B + GEMM_B)
#define NJT    ((VTGT + 127) / 128)   // 393 j-tiles of 128

typedef float f32x4 __attribute__((ext_vector_type(4)));
typedef unsigned int u32;
typedef unsigned int u32x4 __attribute__((ext_vector_type(4)));

__device__ __forceinline__ unsigned short f2bf(float f) {
  union { float f; unsigned u; } v; v.f = f;
  unsigned u = v.u;
  unsigned r = (u + 0x7FFFu + ((u >> 16) & 1u)) >> 16;
  return (unsigned short)r;
}

__device__ __forceinline__ float sigm(float x) {
  return __builtin_amdgcn_rcpf(1.f + __expf(-x));
}
__device__ __forceinline__ float fast_tanh(float x) {
  return 1.f - 2.f * __builtin_amdgcn_rcpf(__expf(2.f * x) + 1.f);
}

// single coherent dword poll (one RTT per sample)
__device__ __forceinline__ u32 cpoll(const u32* p) {
  u32 v;
  asm volatile("global_load_dword %0, %1, off sc0 sc1\n\ts_waitcnt vmcnt(0)"
               : "=v"(v) : "v"(p) : "memory");
  return v;
}
// 4x dwordx4 coherent, single flight (staging)
__device__ __forceinline__ void cload4x4(const u32* p, u32x4& a, u32x4& b,
                                         u32x4& c, u32x4& d) {
  asm volatile(
      "global_load_dwordx4 %0, %4, off sc0 sc1\n\t"
      "global_load_dwordx4 %1, %4, off offset:16 sc0 sc1\n\t"
      "global_load_dwordx4 %2, %4, off offset:32 sc0 sc1\n\t"
      "global_load_dwordx4 %3, %4, off offset:48 sc0 sc1\n\t"
      "s_waitcnt vmcnt(0)"
      : "=v"(a), "=v"(b), "=v"(c), "=v"(d) : "v"(p) : "memory");
}
// 2x dwordx4 coherent at p0 and p1, single flight
__device__ __forceinline__ void cload2(const u32* p0, const u32* p1,
                                       u32x4& a, u32x4& b) {
  asm volatile(
      "global_load_dwordx4 %0, %2, off sc0 sc1\n\t"
      "global_load_dwordx4 %1, %3, off sc0 sc1\n\t"
      "s_waitcnt vmcnt(0)"
      : "=v"(a), "=v"(b) : "v"(p0), "v"(p1) : "memory");
}
__device__ __forceinline__ void cstore(u32* p, u32 v) {
  asm volatile("global_store_dword %0, %1, off sc0 sc1" :: "v"(p), "v"(v) : "memory");
}
__device__ __forceinline__ void cstore4(u32* p, u32x4 v) {
  asm volatile("global_store_dwordx4 %0, %1, off sc0 sc1" :: "v"(p), "v"(v) : "memory");
}

// ---------- encoder: gi = Wih_e @ x_last + bih_e ----------
__global__ void kenc1(const int* source, const float* emb_e, const float* Wih_e,
                      const float* bih_e, float* genc) {
  __shared__ float xs[EMBED];
  int tid = threadIdx.x;
  int tok = source[511];
  if (tid < EMBED) xs[tid] = emb_e[(size_t)tok * EMBED + tid];
  __syncthreads();
  int j = blockIdx.x * 256 + tid;
  const float* w = Wih_e + (size_t)j * EMBED;
  float acc = bih_e[j];
  for (int k = 0; k < EMBED; k += 4) {
    float4 wv = *(const float4*)(w + k);
    acc += wv.x * xs[k] + wv.y * xs[k + 1] + wv.z * xs[k + 2] + wv.w * xs[k + 3];
  }
  genc[j] = acc;
}

// ---------- encoder gates: write tagged h_0 into hs slot 0 ----------
__global__ void kenc2(const float* genc, const float* bhh_e, u32* hs) {
  int e = threadIdx.x; // 512 threads
  float r = sigm(genc[e] + bhh_e[e]);
  float z = sigm(genc[e + 512] + bhh_e[e + 512]);
  float n = tanhf(genc[e + 1024] + r * bhh_e[e + 1024]);
  float h = (1.f - z) * n;
  hs[e] = (__float_as_uint(h) & ~511u) | 256u;  // tag(0) = 256
}

// ---------- GI[t][j] = Wih_d @ relu(emb_d[tok_t]) + bih_d ----------
__global__ __launch_bounds__(256) void kgi(const int* target, const float* emb_d,
                                           const float* Wih_d, const float* bih_d,
                                           float* GI) {
  __shared__ float Xs[32][EMBED];
  int tid = threadIdx.x;
  int j0 = blockIdx.x * 128;
  int t0 = blockIdx.y * 32;
  for (int idx = tid; idx < 32 * EMBED; idx += 256) {
    int tt = idx >> 8, c = idx & 255;
    int t = t0 + tt;
    int tok = (t == 0) ? 0 : target[t - 1];
    float v = emb_d[(size_t)tok * EMBED + c];
    Xs[tt][c] = v > 0.f ? v : 0.f;
  }
  __syncthreads();
  int jl = tid & 127, tg = tid >> 7;
  int j = j0 + jl;
  const float* w = Wih_d + (size_t)j * EMBED;
  float acc[16];
#pragma unroll
  for (int i = 0; i < 16; ++i) acc[i] = 0.f;
  for (int k = 0; k < EMBED; k += 4) {
    float4 wv = *(const float4*)(w + k);
#pragma unroll
    for (int i = 0; i < 16; ++i) {
      int tl = tg * 16 + i;
      acc[i] += wv.x * Xs[tl][k] + wv.y * Xs[tl][k + 1] +
                wv.z * Xs[tl][k + 2] + wv.w * Xs[tl][k + 3];
    }
  }
  float b = bih_d[j];
#pragma unroll
  for (int i = 0; i < 16; ++i) {
    int t = t0 + tg * 16 + i;
    GI[(size_t)t * GATE3 + j] = acc[i] + b;
  }
}

#define DOT4(w, h) (w[0]*h[0] + w[1]*h[1] + w[2]*h[2] + w[3]*h[3])

// ---------- recurrence: 16 blocks x 512 thr, named-SSA weights, 2 antiphase pollers ----------
__device__ void rec_path(int bid, const float* __restrict__ Whh,
                         const float* __restrict__ bhh,
                         const float* __restrict__ GI, u32* hs, u32* stepv,
                         char* SM) {
  int tid = threadIdx.x;
  int p = tid & 15, r = tid >> 4;     // k-slice 0..15, row 0..31
  int e = bid * 32 + r;
  int k0 = p * 32;
  float* hbuf = (float*)SM;           // [2][576] padded stride 36 per 32
  // weights as 24 NAMED f32x4 SSA values -> cannot be memory-demoted
  const f32x4* Wr = (const f32x4*)(Whh + (size_t)e * HIDDEN + k0);
  const f32x4* Wz = (const f32x4*)(Whh + (size_t)(e + 512) * HIDDEN + k0);
  const f32x4* Wn = (const f32x4*)(Whh + (size_t)(e + 1024) * HIDDEN + k0);
  f32x4 wr0 = Wr[0], wr1 = Wr[1], wr2 = Wr[2], wr3 = Wr[3],
        wr4 = Wr[4], wr5 = Wr[5], wr6 = Wr[6], wr7 = Wr[7];
  f32x4 wz0 = Wz[0], wz1 = Wz[1], wz2 = Wz[2], wz3 = Wz[3],
        wz4 = Wz[4], wz5 = Wz[5], wz6 = Wz[6], wz7 = Wz[7];
  f32x4 wn0 = Wn[0], wn1 = Wn[1], wn2 = Wn[2], wn3 = Wn[3],
        wn4 = Wn[4], wn5 = Wn[5], wn6 = Wn[6], wn7 = Wn[7];
  float br = bhh[e], bz = bhh[e + 512], bn = bhh[e + 1024];
  float hold = __uint_as_float(hs[e] & ~511u);   // h^0[e], register-resident
  __builtin_amdgcn_s_setprio(1);
  // poll geometry (waves 0 AND 1, identical antiphase work):
  // lane handles dwords d0=lane*4 (.. +3) and d0+256
  int lane = tid & 63;
  int d0 = lane * 4;
  int i0 = ((d0 >> 5) * 36) + (d0 & 31);
  int i1 = (((d0 + 256) >> 5) * 36) + (d0 & 31);
  int w = tid >> 6;                               // wave 0..7 (rows 4w..4w+3)
  u32* pubbase = hs + bid * 32 + w * 4;           // + (t+1)*HIDDEN later
  for (int t = 0; t < TLEN; ++t) {
    int par = t & 1;
    float gie = 0.f, giz = 0.f, gin = 0.f;
    if (p == 0) {
      const float* git = GI + (size_t)t * GATE3;
      gie = git[e]; giz = git[e + 512]; gin = git[e + 1024];
    }
    if (tid < 128) {   // waves 0 and 1: independent antiphase pollers, idempotent writes
      const u32* s0 = hs + (size_t)t * HIDDEN + d0;
      const u32* s1 = s0 + 256;
      u32 want = 256u + ((u32)t & 255u);
      u32x4 a, b;
      for (;;) {
        cload2(s0, s1, a, b);
        u32 bad = 0;
#pragma unroll
        for (int q = 0; q < 4; ++q) bad |= (a[q] ^ want) | (b[q] ^ want);
        if (!__any((bad & 511u) != 0u)) break;
      }
      f32x4 fa, fb;
#pragma unroll
      for (int q = 0; q < 4; ++q) {
        fa[q] = __uint_as_float(a[q] & ~511u);
        fb[q] = __uint_as_float(b[q] & ~511u);
      }
      *(f32x4*)&hbuf[par * 576 + i0] = fa;
      *(f32x4*)&hbuf[par * 576 + i1] = fb;
    }
    __syncthreads();
    if (bid == 0 && tid == 0) cstore(stepv, (u32)t);  // slot t globally visible
    const f32x4* hp4 = (const f32x4*)(hbuf + par * 576 + p * 36);
    f32x4 h0 = hp4[0], h1 = hp4[1], h2 = hp4[2], h3 = hp4[3],
          h4 = hp4[4], h5 = hp4[5], h6 = hp4[6], h7 = hp4[7];
    float pr = DOT4(wr0, h0) + DOT4(wr1, h1) + DOT4(wr2, h2) + DOT4(wr3, h3) +
               DOT4(wr4, h4) + DOT4(wr5, h5) + DOT4(wr6, h6) + DOT4(wr7, h7);
    float pz = DOT4(wz0, h0) + DOT4(wz1, h1) + DOT4(wz2, h2) + DOT4(wz3, h3) +
               DOT4(wz4, h4) + DOT4(wz5, h5) + DOT4(wz6, h6) + DOT4(wz7, h7);
    float pn = DOT4(wn0, h0) + DOT4(wn1, h1) + DOT4(wn2, h2) + DOT4(wn3, h3) +
               DOT4(wn4, h4) + DOT4(wn5, h5) + DOT4(wn6, h6) + DOT4(wn7, h7);
#pragma unroll
    for (int m = 1; m < 16; m <<= 1) {
      pr += __shfl_xor(pr, m);
      pz += __shfl_xor(pz, m);
      pn += __shfl_xor(pn, m);
    }
    u32 pk = 0;
    if (p == 0) {
      float rg = sigm(gie + pr + br);
      float z  = sigm(giz + pz + bz);
      float n  = fast_tanh(gin + rg * (pn + bn));
      float hnew = (1.f - z) * n + z * hold;
      hold = hnew;
      pk = (__float_as_uint(hnew) & ~511u) | (256u + ((u32)(t + 1) & 255u));
    }
    // gather the wave's 4 row-values (lanes 0,16,32,48) -> one dwordx4 store
    u32x4 o;
    o[0] = __shfl(pk, 0);  o[1] = __shfl(pk, 16);
    o[2] = __shfl(pk, 32); o[3] = __shfl(pk, 48);
    if ((tid & 63) == 0) cstore4(pubbase + (size_t)(t + 1) * HIDDEN, o);
    // no tail barrier: next step's pollers write the other hbuf parity
  }
  if (bid == 0 && tid < 64) {  // confirm final slot 512 -> stepv = 512
    const u32* s0 = hs + (size_t)TLEN * HIDDEN + d0;
    const u32* s1 = s0 + 256;
    u32 want = 256u + ((u32)TLEN & 255u);
    u32x4 a, b;
    for (;;) {
      cload2(s0, s1, a, b);
      u32 bad = 0;
#pragma unroll
      for (int q = 0; q < 4; ++q) bad |= (a[q] ^ want) | (b[q] ^ want);
      if (!__any((bad & 511u) != 0u)) break;
    }
    if (tid == 0) cstore(stepv, (u32)TLEN);
  }
}

// ---------- GEMM path: tag-verified A staging, on-the-fly bf16 B, fused row-sum ----------
__device__ void gemm_path(int g, const u32* hs, u32* stepv, const float* Wout,
                          const float* bout, float* rs, float* out, char* SM) {
  unsigned short* As = (unsigned short*)SM;       // [64][520] bf16
  float* rsum = (float*)(SM + 64 * 520 * 2);      // [64]
  int tid = threadIdx.x;
  int w = tid >> 6, lane = tid & 63;
  int jl = lane & 15, kq = lane >> 4;
  int srow = tid >> 3, scg = tid & 7;             // stage: row 0..63, 64-dword group
  if (tid < 64) rsum[tid] = 0.f;
  for (int t0i = 0; t0i < 8; ++t0i) {
    int t0 = t0i * 64;
    if (tid == 0) {  // sleep-throttled progress hint (tags stay authoritative)
      while ((int)cpoll(stepv) < t0 + 64) __builtin_amdgcn_s_sleep(16);
    }
    __syncthreads();
    // stage A tile: rows t0..t0+63 from tagged hs slots t0+1..t0+64
    int slot = t0 + srow + 1;
    u32 want = 256u + ((u32)slot & 255u);
    const u32* sbase = hs + (size_t)slot * HIDDEN + scg * 64;
#pragma unroll
    for (int b = 0; b < 4; ++b) {
      const u32* sp = sbase + b * 16;
      u32x4 c0, c1, c2, c3;
      for (;;) {
        cload4x4(sp, c0, c1, c2, c3);
        u32 bad = 0;
#pragma unroll
        for (int q = 0; q < 4; ++q)
          bad |= (c0[q] ^ want) | (c1[q] ^ want) | (c2[q] ^ want) | (c3[q] ^ want);
        if (!(bad & 511u)) break;
      }
      u32 dw[8];
#pragma unroll
      for (int q = 0; q < 4; ++q) {
        u32x4 cq = (q == 0) ? c0 : (q == 1) ? c1 : (q == 2) ? c2 : c3;
        float f0 = __uint_as_float(cq[0] & ~511u);
        float f1 = __uint_as_float(cq[1] & ~511u);
        float f2 = __uint_as_float(cq[2] & ~511u);
        float f3 = __uint_as_float(cq[3] & ~511u);
        dw[q * 2]     = (u32)f2bf(f0) | ((u32)f2bf(f1) << 16);
        dw[q * 2 + 1] = (u32)f2bf(f2) | ((u32)f2bf(f3) << 16);
      }
      *(u32x4*)&As[srow * 520 + scg * 64 + b * 16]     = *(u32x4*)&dw[0];
      *(u32x4*)&As[srow * 520 + scg * 64 + b * 16 + 8] = *(u32x4*)&dw[4];
    }
    __syncthreads();
    for (int jt = g; jt < NJT; jt += GEMM_B) {
      int j = jt * 128 + w * 16 + jl;
      int jc = j < VTGT ? j : VTGT - 1;
      const float* Bp = Wout + (size_t)jc * HIDDEN + kq * 8;
      f32x4 acc[4];
#pragma unroll
      for (int i = 0; i < 4; ++i) acc[i] = (f32x4)(0.f);
#pragma unroll
      for (int ks = 0; ks < 16; ++ks) {
        float4 b0 = *(const float4*)(Bp + ks * 32);
        float4 b1 = *(const float4*)(Bp + ks * 32 + 4);
        u32x4 bf;
        bf[0] = (u32)f2bf(b0.x) | ((u32)f2bf(b0.y) << 16);
        bf[1] = (u32)f2bf(b0.z) | ((u32)f2bf(b0.w) << 16);
        bf[2] = (u32)f2bf(b1.x) | ((u32)f2bf(b1.y) << 16);
        bf[3] = (u32)f2bf(b1.z) | ((u32)f2bf(b1.w) << 16);
#pragma unroll
        for (int tq = 0; tq < 4; ++tq) {
          u32x4 af = *(const u32x4*)&As[(tq * 16 + jl) * 520 + ks * 32 + kq * 8];
          asm volatile("v_mfma_f32_16x16x32_bf16 %0, %1, %2, %0"
                       : "+v"(acc[tq]) : "v"(af), "v"(bf));
        }
      }
      asm volatile("s_nop 7\n\ts_nop 7\n\ts_nop 7" ::);
      bool jok = j < VTGT;
      float bj = jok ? bout[j] : 0.f;
#pragma unroll
      for (int tq = 0; tq < 4; ++tq) {
#pragma unroll
        for (int rr = 0; rr < 4; ++rr) {
          int t = t0 + tq * 16 + kq * 4 + rr;  // D: row=(lane>>4)*4+reg, col=lane&15
          float lg = acc[tq][rr] + bj;
          if (jok) out[(size_t)t * VTGT + j] = lg;
          float ex = jok ? __expf(lg) : 0.f;
#pragma unroll
          for (int m = 1; m < 16; m <<= 1) ex += __shfl_xor(ex, m);
          if (jl == 0) atomicAdd(&rsum[tq * 16 + kq * 4 + rr], ex);
        }
      }
    }
    __syncthreads();  // all As reads + rsum adds done
    if (tid < 64) {
      atomicAdd(rs + t0 + tid, rsum[tid]);
      rsum[tid] = 0.f;
    }
  }
}

// ---------- fused mega-kernel: 16 rec blocks + 224 persistent GEMM blocks ----------
__global__ __launch_bounds__(512, 2) void kmain(const float* Whh, const float* bhh,
                                                const float* GI, u32* hs, u32* stepv,
                                                const float* Wout, const float* bout,
                                                float* rs, float* out) {
  __shared__ __align__(16) char SM[64 * 520 * 2 + 256];  // As+rsum / hbuf union
  int bid = blockIdx.x;
  if (bid < REC_B) rec_path(bid, Whh, bhh, GI, hs, stepv, SM);
  else gemm_path(bid - REC_B, hs, stepv, Wout, bout, rs, out, SM);
}

// ---------- logp = logits - log(rowsum), single pass ----------
__global__ __launch_bounds__(1024) void klsub(float* out, const float* rs) {
  int t = blockIdx.x;
  float l = logf(rs[t]);
  float* row = out + (size_t)t * VTGT;
  for (int jj = threadIdx.x; jj < VTGT; jj += 1024) row[jj] -= l;
}

extern "C" void kernel_launch(void* const* d_in, const int* in_sizes, int n_in,
                              void* d_out, int out_size, void* d_ws, size_t ws_size,
                              hipStream_t stream) {
  const int*   source = (const int*)d_in[0];
  const int*   target = (const int*)d_in[1];
  const float* emb_e  = (const float*)d_in[2];
  const float* Wih_e  = (const float*)d_in[3];
  // d_in[4] = Whh_e: unused (h0 == 0)
  const float* bih_e  = (const float*)d_in[5];
  const float* bhh_e  = (const float*)d_in[6];
  const float* emb_d  = (const float*)d_in[7];
  const float* Wih_d  = (const float*)d_in[8];
  const float* Whh_d  = (const float*)d_in[9];
  const float* bih_d  = (const float*)d_in[10];
  const float* bhh_d  = (const float*)d_in[11];
  const float* Wout   = (const float*)d_in[12];
  const float* bout   = (const float*)d_in[13];
  float* out = (float*)d_out;
  char* ws = (char*)d_ws;

  // ws layout (bytes), 256-aligned
  float* GI    = (float*)(ws + 0);           // 3,145,728
  u32*   hs    = (u32*)(ws + 3145728);       // 1,050,624 (513 x 512 tagged f32)
  u32*   stepv = (u32*)(ws + 4196352);       //       128
  float* rs    = (float*)(ws + 4196480);     //     2,048 (row sum-exp)
  float* genc  = (float*)(ws + 4198528);     //     6,144
  // total ws use ~4.2 MB

  hipMemsetAsync(hs, 0, 1052800, stream);    // hs tags + stepv + rs
  kenc1<<<6, 256, 0, stream>>>(source, emb_e, Wih_e, bih_e, genc);
  kenc2<<<1, 512, 0, stream>>>(genc, bhh_e, hs);
  kgi<<<dim3(12, 16), 256, 0, stream>>>(target, emb_d, Wih_d, bih_d, GI);
  kmain<<<NBLK, 512, 0, stream>>>(Whh_d, bhh_d, GI, hs, stepv, Wout, bout, rs, out);
  klsub<<<512, 1024, 0, stream>>>(out, rs);
}

// Round 11
// 859.626 us; speedup vs baseline: 1.0523x; 1.0437x over previous
//
#include <hip/hip_runtime.h>
#include <stdint.h>

#define HIDDEN 512
#define EMBED  256
#define VTGT   50257
#define TLEN   512
#define GATE3  1536
#define REC_B  16
#define GEMM_B 224
#define NBLK   (REC_B + GEMM_B)
#define NJT    ((VTGT + 127) / 128)   // 393 j-tiles of 128

typedef float f32x4 __attribute__((ext_vector_type(4)));
typedef unsigned int u32;
typedef unsigned int u32x4 __attribute__((ext_vector_type(4)));

__device__ __forceinline__ unsigned short f2bf(float f) {
  union { float f; unsigned u; } v; v.f = f;
  unsigned u = v.u;
  unsigned r = (u + 0x7FFFu + ((u >> 16) & 1u)) >> 16;
  return (unsigned short)r;
}

__device__ __forceinline__ float sigm(float x) {
  return __builtin_amdgcn_rcpf(1.f + __expf(-x));
}
__device__ __forceinline__ float fast_tanh(float x) {
  return 1.f - 2.f * __builtin_amdgcn_rcpf(__expf(2.f * x) + 1.f);
}

// ---- device-scope (cross-XCD) primitives: sc0 sc1 ----
__device__ __forceinline__ u32 cpoll(const u32* p) {
  u32 v;
  asm volatile("global_load_dword %0, %1, off sc0 sc1\n\ts_waitcnt vmcnt(0)"
               : "=v"(v) : "v"(p) : "memory");
  return v;
}
__device__ __forceinline__ void cload4x4(const u32* p, u32x4& a, u32x4& b,
                                         u32x4& c, u32x4& d) {
  asm volatile(
      "global_load_dwordx4 %0, %4, off sc0 sc1\n\t"
      "global_load_dwordx4 %1, %4, off offset:16 sc0 sc1\n\t"
      "global_load_dwordx4 %2, %4, off offset:32 sc0 sc1\n\t"
      "global_load_dwordx4 %3, %4, off offset:48 sc0 sc1\n\t"
      "s_waitcnt vmcnt(0)"
      : "=v"(a), "=v"(b), "=v"(c), "=v"(d) : "v"(p) : "memory");
}
__device__ __forceinline__ void cload2(const u32* p0, const u32* p1,
                                       u32x4& a, u32x4& b) {
  asm volatile(
      "global_load_dwordx4 %0, %2, off sc0 sc1\n\t"
      "global_load_dwordx4 %1, %3, off sc0 sc1\n\t"
      "s_waitcnt vmcnt(0)"
      : "=v"(a), "=v"(b) : "v"(p0), "v"(p1) : "memory");
}
__device__ __forceinline__ void cstore(u32* p, u32 v) {
  asm volatile("global_store_dword %0, %1, off sc0 sc1" :: "v"(p), "v"(v) : "memory");
}
__device__ __forceinline__ void cstore4(u32* p, u32x4 v) {
  asm volatile("global_store_dwordx4 %0, %1, off sc0 sc1" :: "v"(p), "v"(v) : "memory");
}
// ---- XCD-scope (same-die L2) primitives: sc0 only ----
__device__ __forceinline__ void cload2_l(const u32* p0, const u32* p1,
                                         u32x4& a, u32x4& b) {
  asm volatile(
      "global_load_dwordx4 %0, %2, off sc0\n\t"
      "global_load_dwordx4 %1, %3, off sc0\n\t"
      "s_waitcnt vmcnt(0)"
      : "=v"(a), "=v"(b) : "v"(p0), "v"(p1) : "memory");
}
__device__ __forceinline__ void cstore4_l(u32* p, u32x4 v) {
  asm volatile("global_store_dwordx4 %0, %1, off sc0" :: "v"(p), "v"(v) : "memory");
}

// ---------- encoder: gi = Wih_e @ x_last + bih_e ----------
__global__ void kenc1(const int* source, const float* emb_e, const float* Wih_e,
                      const float* bih_e, float* genc) {
  __shared__ float xs[EMBED];
  int tid = threadIdx.x;
  int tok = source[511];
  if (tid < EMBED) xs[tid] = emb_e[(size_t)tok * EMBED + tid];
  __syncthreads();
  int j = blockIdx.x * 256 + tid;
  const float* w = Wih_e + (size_t)j * EMBED;
  float acc = bih_e[j];
  for (int k = 0; k < EMBED; k += 4) {
    float4 wv = *(const float4*)(w + k);
    acc += wv.x * xs[k] + wv.y * xs[k + 1] + wv.z * xs[k + 2] + wv.w * xs[k + 3];
  }
  genc[j] = acc;
}

// ---------- encoder gates: tagged h_0 into local hs AND mirror hsm ----------
__global__ void kenc2(const float* genc, const float* bhh_e, u32* hs, u32* hsm) {
  int e = threadIdx.x; // 512 threads
  float r = sigm(genc[e] + bhh_e[e]);
  float z = sigm(genc[e + 512] + bhh_e[e + 512]);
  float n = tanhf(genc[e + 1024] + r * bhh_e[e + 1024]);
  float h = (1.f - z) * n;
  u32 pk = (__float_as_uint(h) & ~511u) | 256u;  // tag(0) = 256
  hs[e] = pk;
  hsm[e] = pk;
}

// ---------- GI[t][j] = Wih_d @ relu(emb_d[tok_t]) + bih_d ----------
__global__ __launch_bounds__(256) void kgi(const int* target, const float* emb_d,
                                           const float* Wih_d, const float* bih_d,
                                           float* GI) {
  __shared__ float Xs[32][EMBED];
  int tid = threadIdx.x;
  int j0 = blockIdx.x * 128;
  int t0 = blockIdx.y * 32;
  for (int idx = tid; idx < 32 * EMBED; idx += 256) {
    int tt = idx >> 8, c = idx & 255;
    int t = t0 + tt;
    int tok = (t == 0) ? 0 : target[t - 1];
    float v = emb_d[(size_t)tok * EMBED + c];
    Xs[tt][c] = v > 0.f ? v : 0.f;
  }
  __syncthreads();
  int jl = tid & 127, tg = tid >> 7;
  int j = j0 + jl;
  const float* w = Wih_d + (size_t)j * EMBED;
  float acc[16];
#pragma unroll
  for (int i = 0; i < 16; ++i) acc[i] = 0.f;
  for (int k = 0; k < EMBED; k += 4) {
    float4 wv = *(const float4*)(w + k);
#pragma unroll
    for (int i = 0; i < 16; ++i) {
      int tl = tg * 16 + i;
      acc[i] += wv.x * Xs[tl][k] + wv.y * Xs[tl][k + 1] +
                wv.z * Xs[tl][k + 2] + wv.w * Xs[tl][k + 3];
    }
  }
  float b = bih_d[j];
#pragma unroll
  for (int i = 0; i < 16; ++i) {
    int t = t0 + tg * 16 + i;
    GI[(size_t)t * GATE3 + j] = acc[i] + b;
  }
}

#define DOT4(w, h) (w[0]*h[0] + w[1]*h[1] + w[2]*h[2] + w[3]*h[3])

// ---------- recurrence: 16 same-XCD blocks, local-L2 poll + device mirror ----------
__device__ void rec_path(int slot, const float* __restrict__ Whh,
                         const float* __restrict__ bhh,
                         const float* __restrict__ GI, u32* hs, u32* hsm,
                         u32* stepv, char* SM) {
  int tid = threadIdx.x;
  int p = tid & 15, r = tid >> 4;     // k-slice 0..15, row 0..31
  int e = slot * 32 + r;
  int k0 = p * 32;
  float* hbuf = (float*)SM;           // [2][576] padded stride 36 per 32
  const f32x4* Wr = (const f32x4*)(Whh + (size_t)e * HIDDEN + k0);
  const f32x4* Wz = (const f32x4*)(Whh + (size_t)(e + 512) * HIDDEN + k0);
  const f32x4* Wn = (const f32x4*)(Whh + (size_t)(e + 1024) * HIDDEN + k0);
  f32x4 wr0 = Wr[0], wr1 = Wr[1], wr2 = Wr[2], wr3 = Wr[3],
        wr4 = Wr[4], wr5 = Wr[5], wr6 = Wr[6], wr7 = Wr[7];
  f32x4 wz0 = Wz[0], wz1 = Wz[1], wz2 = Wz[2], wz3 = Wz[3],
        wz4 = Wz[4], wz5 = Wz[5], wz6 = Wz[6], wz7 = Wz[7];
  f32x4 wn0 = Wn[0], wn1 = Wn[1], wn2 = Wn[2], wn3 = Wn[3],
        wn4 = Wn[4], wn5 = Wn[5], wn6 = Wn[6], wn7 = Wn[7];
  float br = bhh[e], bz = bhh[e + 512], bn = bhh[e + 1024];
  float hold = __uint_as_float(hs[e] & ~511u);   // h^0[e]
  __builtin_amdgcn_s_setprio(1);
  int lane = tid & 63;
  int d0 = lane * 4;
  int i0 = ((d0 >> 5) * 36) + (d0 & 31);
  int i1 = (((d0 + 256) >> 5) * 36) + (d0 & 31);
  int w = tid >> 6;                               // wave 0..7 (rows 4w..4w+3)
  u32* pub_l = hs + slot * 32 + w * 4;
  u32* pub_m = hsm + slot * 32 + w * 4;
  int fb = 0;                                     // fallback engagement count
  for (int t = 0; t < TLEN; ++t) {
    int par = t & 1;
    float gie = 0.f, giz = 0.f, gin = 0.f;
    if (p == 0) {
      const float* git = GI + (size_t)t * GATE3;
      gie = git[e]; giz = git[e + 512]; gin = git[e + 1024];
    }
    if (tid < 128) {   // waves 0,1: antiphase pollers (local L2 fast path)
      const u32* s0 = hs + (size_t)t * HIDDEN + d0;
      const u32* s1 = s0 + 256;
      u32 want = 256u + ((u32)t & 255u);
      u32x4 a, b;
      bool ok = false;
      int tries = (fb >= 8) ? 0 : 24;
      for (int it = 0; it < tries && !ok; ++it) {
        cload2_l(s0, s1, a, b);
        u32 bad = 0;
#pragma unroll
        for (int q = 0; q < 4; ++q) bad |= (a[q] ^ want) | (b[q] ^ want);
        ok = !__any((bad & 511u) != 0u);
      }
      if (!ok) {       // graceful degrade: device-scope mirror poll (always correct)
        ++fb;
        const u32* m0 = hsm + (size_t)t * HIDDEN + d0;
        const u32* m1 = m0 + 256;
        do {
          cload2(m0, m1, a, b);
          u32 bad = 0;
#pragma unroll
          for (int q = 0; q < 4; ++q) bad |= (a[q] ^ want) | (b[q] ^ want);
          ok = !__any((bad & 511u) != 0u);
        } while (!ok);
      }
      f32x4 fa, fc;
#pragma unroll
      for (int q = 0; q < 4; ++q) {
        fa[q] = __uint_as_float(a[q] & ~511u);
        fc[q] = __uint_as_float(b[q] & ~511u);
      }
      *(f32x4*)&hbuf[par * 576 + i0] = fa;
      *(f32x4*)&hbuf[par * 576 + i1] = fc;
    }
    __syncthreads();
    if (slot == 0 && tid == 128) cstore(stepv, (u32)t);  // hint from non-poller wave
    const f32x4* hp4 = (const f32x4*)(hbuf + par * 576 + p * 36);
    f32x4 h0 = hp4[0], h1 = hp4[1], h2 = hp4[2], h3 = hp4[3],
          h4 = hp4[4], h5 = hp4[5], h6 = hp4[6], h7 = hp4[7];
    float pr = DOT4(wr0, h0) + DOT4(wr1, h1) + DOT4(wr2, h2) + DOT4(wr3, h3) +
               DOT4(wr4, h4) + DOT4(wr5, h5) + DOT4(wr6, h6) + DOT4(wr7, h7);
    float pz = DOT4(wz0, h0) + DOT4(wz1, h1) + DOT4(wz2, h2) + DOT4(wz3, h3) +
               DOT4(wz4, h4) + DOT4(wz5, h5) + DOT4(wz6, h6) + DOT4(wz7, h7);
    float pn = DOT4(wn0, h0) + DOT4(wn1, h1) + DOT4(wn2, h2) + DOT4(wn3, h3) +
               DOT4(wn4, h4) + DOT4(wn5, h5) + DOT4(wn6, h6) + DOT4(wn7, h7);
#pragma unroll
    for (int m = 1; m < 16; m <<= 1) {
      pr += __shfl_xor(pr, m);
      pz += __shfl_xor(pz, m);
      pn += __shfl_xor(pn, m);
    }
    u32 pk = 0;
    if (p == 0) {
      float rg = sigm(gie + pr + br);
      float z  = sigm(giz + pz + bz);
      float n  = fast_tanh(gin + rg * (pn + bn));
      float hnew = (1.f - z) * n + z * hold;
      hold = hnew;
      pk = (__float_as_uint(hnew) & ~511u) | (256u + ((u32)(t + 1) & 255u));
    }
    u32x4 o;
    o[0] = __shfl(pk, 0);  o[1] = __shfl(pk, 16);
    o[2] = __shfl(pk, 32); o[3] = __shfl(pk, 48);
    if ((tid & 63) == 0) {
      cstore4_l(pub_l + (size_t)(t + 1) * HIDDEN, o);  // XCD-local (fast path)
      cstore4(pub_m + (size_t)(t + 1) * HIDDEN, o);    // device mirror (for GEMM)
    }
  }
  if (slot == 0 && tid < 64) {  // confirm final slot 512 in MIRROR -> stepv = 512
    const u32* m0 = hsm + (size_t)TLEN * HIDDEN + d0;
    const u32* m1 = m0 + 256;
    u32 want = 256u + ((u32)TLEN & 255u);
    u32x4 a, b;
    for (;;) {
      cload2(m0, m1, a, b);
      u32 bad = 0;
#pragma unroll
      for (int q = 0; q < 4; ++q) bad |= (a[q] ^ want) | (b[q] ^ want);
      if (!__any((bad & 511u) != 0u)) break;
    }
    if (tid == 0) cstore(stepv, (u32)TLEN);
  }
}

// ---------- GEMM path: stages from the device-scope mirror (unchanged protocol) ----------
__device__ void gemm_path(int g, const u32* hsm, u32* stepv, const float* Wout,
                          const float* bout, float* rs, float* out, char* SM) {
  unsigned short* As = (unsigned short*)SM;       // [64][520] bf16
  float* rsum = (float*)(SM + 64 * 520 * 2);      // [64]
  int tid = threadIdx.x;
  int w = tid >> 6, lane = tid & 63;
  int jl = lane & 15, kq = lane >> 4;
  int srow = tid >> 3, scg = tid & 7;             // stage: row 0..63, 64-dword group
  if (tid < 64) rsum[tid] = 0.f;
  for (int t0i = 0; t0i < 8; ++t0i) {
    int t0 = t0i * 64;
    if (tid == 0) {  // sleep-throttled progress hint (tags stay authoritative)
      while ((int)cpoll(stepv) < t0 + 64) __builtin_amdgcn_s_sleep(16);
    }
    __syncthreads();
    int slot = t0 + srow + 1;
    u32 want = 256u + ((u32)slot & 255u);
    const u32* sbase = hsm + (size_t)slot * HIDDEN + scg * 64;
#pragma unroll
    for (int b = 0; b < 4; ++b) {
      const u32* sp = sbase + b * 16;
      u32x4 c0, c1, c2, c3;
      for (;;) {
        cload4x4(sp, c0, c1, c2, c3);
        u32 bad = 0;
#pragma unroll
        for (int q = 0; q < 4; ++q)
          bad |= (c0[q] ^ want) | (c1[q] ^ want) | (c2[q] ^ want) | (c3[q] ^ want);
        if (!(bad & 511u)) break;
      }
      u32 dw[8];
#pragma unroll
      for (int q = 0; q < 4; ++q) {
        u32x4 cq = (q == 0) ? c0 : (q == 1) ? c1 : (q == 2) ? c2 : c3;
        float f0 = __uint_as_float(cq[0] & ~511u);
        float f1 = __uint_as_float(cq[1] & ~511u);
        float f2 = __uint_as_float(cq[2] & ~511u);
        float f3 = __uint_as_float(cq[3] & ~511u);
        dw[q * 2]     = (u32)f2bf(f0) | ((u32)f2bf(f1) << 16);
        dw[q * 2 + 1] = (u32)f2bf(f2) | ((u32)f2bf(f3) << 16);
      }
      *(u32x4*)&As[srow * 520 + scg * 64 + b * 16]     = *(u32x4*)&dw[0];
      *(u32x4*)&As[srow * 520 + scg * 64 + b * 16 + 8] = *(u32x4*)&dw[4];
    }
    __syncthreads();
    for (int jt = g; jt < NJT; jt += GEMM_B) {
      int j = jt * 128 + w * 16 + jl;
      int jc = j < VTGT ? j : VTGT - 1;
      const float* Bp = Wout + (size_t)jc * HIDDEN + kq * 8;
      f32x4 acc[4];
#pragma unroll
      for (int i = 0; i < 4; ++i) acc[i] = (f32x4)(0.f);
#pragma unroll
      for (int ks = 0; ks < 16; ++ks) {
        float4 b0 = *(const float4*)(Bp + ks * 32);
        float4 b1 = *(const float4*)(Bp + ks * 32 + 4);
        u32x4 bf;
        bf[0] = (u32)f2bf(b0.x) | ((u32)f2bf(b0.y) << 16);
        bf[1] = (u32)f2bf(b0.z) | ((u32)f2bf(b0.w) << 16);
        bf[2] = (u32)f2bf(b1.x) | ((u32)f2bf(b1.y) << 16);
        bf[3] = (u32)f2bf(b1.z) | ((u32)f2bf(b1.w) << 16);
#pragma unroll
        for (int tq = 0; tq < 4; ++tq) {
          u32x4 af = *(const u32x4*)&As[(tq * 16 + jl) * 520 + ks * 32 + kq * 8];
          asm volatile("v_mfma_f32_16x16x32_bf16 %0, %1, %2, %0"
                       : "+v"(acc[tq]) : "v"(af), "v"(bf));
        }
      }
      asm volatile("s_nop 7\n\ts_nop 7\n\ts_nop 7" ::);
      bool jok = j < VTGT;
      float bj = jok ? bout[j] : 0.f;
#pragma unroll
      for (int tq = 0; tq < 4; ++tq) {
#pragma unroll
        for (int rr = 0; rr < 4; ++rr) {
          int t = t0 + tq * 16 + kq * 4 + rr;  // D: row=(lane>>4)*4+reg, col=lane&15
          float lg = acc[tq][rr] + bj;
          if (jok) out[(size_t)t * VTGT + j] = lg;
          float ex = jok ? __expf(lg) : 0.f;
#pragma unroll
          for (int m = 1; m < 16; m <<= 1) ex += __shfl_xor(ex, m);
          if (jl == 0) atomicAdd(&rsum[tq * 16 + kq * 4 + rr], ex);
        }
      }
    }
    __syncthreads();
    if (tid < 64) {
      atomicAdd(rs + t0 + tid, rsum[tid]);
      rsum[tid] = 0.f;
    }
  }
}

// ---------- fused mega-kernel with placement-aware role assignment ----------
__global__ __launch_bounds__(512, 2) void kmain(const float* Whh, const float* bhh,
                                                const float* GI, u32* hs, u32* hsm,
                                                u32* stepv, u32* ctl,
                                                const float* Wout, const float* bout,
                                                float* rs, float* out) {
  __shared__ __align__(16) char SM[64 * 520 * 2 + 256];
  __shared__ int role;
  int tid = threadIdx.x;
  if (tid == 0) {
    u32 xcc;
    asm volatile("s_getreg_b32 %0, hwreg(HW_REG_XCC_ID)" : "=s"(xcc));
    xcc &= 7u;
    u32 myt = __hip_atomic_fetch_add(&ctl[xcc], 1u, __ATOMIC_RELAXED,
                                     __HIP_MEMORY_SCOPE_AGENT);
    __hip_atomic_fetch_add(&ctl[8], 1u, __ATOMIC_RELEASE, __HIP_MEMORY_SCOPE_AGENT);
    while (__hip_atomic_load(&ctl[8], __ATOMIC_ACQUIRE, __HIP_MEMORY_SCOPE_AGENT)
           < (u32)NBLK)
      __builtin_amdgcn_s_sleep(8);
    int rx = 0;   // first XCD with >= REC_B blocks (exists by pigeonhole)
    for (int x = 0; x < 8; ++x) {
      u32 c = __hip_atomic_load(&ctl[x], __ATOMIC_RELAXED, __HIP_MEMORY_SCOPE_AGENT);
      if (c >= (u32)REC_B) { rx = x; break; }
    }
    if ((int)xcc == rx && myt < (u32)REC_B) {
      role = (int)myt;                 // rec slot 0..15, all on one XCD
    } else {
      role = -1 - (int)__hip_atomic_fetch_add(&ctl[9], 1u, __ATOMIC_RELAXED,
                                              __HIP_MEMORY_SCOPE_AGENT);
    }
  }
  __syncthreads();
  int rl = role;
  if (rl >= 0) rec_path(rl, Whh, bhh, GI, hs, hsm, stepv, SM);
  else gemm_path(-1 - rl, hsm, stepv, Wout, bout, rs, out, SM);
}

// ---------- logp = logits - log(rowsum), single pass ----------
__global__ __launch_bounds__(1024) void klsub(float* out, const float* rs) {
  int t = blockIdx.x;
  float l = logf(rs[t]);
  float* row = out + (size_t)t * VTGT;
  for (int jj = threadIdx.x; jj < VTGT; jj += 1024) row[jj] -= l;
}

extern "C" void kernel_launch(void* const* d_in, const int* in_sizes, int n_in,
                              void* d_out, int out_size, void* d_ws, size_t ws_size,
                              hipStream_t stream) {
  const int*   source = (const int*)d_in[0];
  const int*   target = (const int*)d_in[1];
  const float* emb_e  = (const float*)d_in[2];
  const float* Wih_e  = (const float*)d_in[3];
  // d_in[4] = Whh_e: unused (h0 == 0)
  const float* bih_e  = (const float*)d_in[5];
  const float* bhh_e  = (const float*)d_in[6];
  const float* emb_d  = (const float*)d_in[7];
  const float* Wih_d  = (const float*)d_in[8];
  const float* Whh_d  = (const float*)d_in[9];
  const float* bih_d  = (const float*)d_in[10];
  const float* bhh_d  = (const float*)d_in[11];
  const float* Wout   = (const float*)d_in[12];
  const float* bout   = (const float*)d_in[13];
  float* out = (float*)d_out;
  char* ws = (char*)d_ws;

  // ws layout (bytes), 256-aligned
  float* GI    = (float*)(ws + 0);           // 3,145,728
  u32*   hs    = (u32*)(ws + 3145728);       // 1,050,624 (local, 513 x 512 tagged)
  u32*   hsm   = (u32*)(ws + 4196352);       // 1,050,624 (device mirror)
  u32*   stepv = (u32*)(ws + 5246976);       //       128
  float* rs    = (float*)(ws + 5247104);     //     2,048 (row sum-exp)
  u32*   ctl   = (u32*)(ws + 5249152);       //       128 (role tickets)
  float* genc  = (float*)(ws + 5249280);     //     6,144
  // total ws use ~5.3 MB

  hipMemsetAsync(ws + 3145728, 0, 2103552, stream);  // hs+hsm tags, stepv, rs, ctl
  kenc1<<<6, 256, 0, stream>>>(source, emb_e, Wih_e, bih_e, genc);
  kenc2<<<1, 512, 0, stream>>>(genc, bhh_e, hs, hsm);
  kgi<<<dim3(12, 16), 256, 0, stream>>>(target, emb_d, Wih_d, bih_d, GI);
  kmain<<<NBLK, 512, 0, stream>>>(Whh_d, bhh_d, GI, hs, hsm, stepv, ctl,
                                  Wout, bout, rs, out);
  klsub<<<512, 1024, 0, stream>>>(out, rs);
}